// Round 1
// baseline (520.740 us; speedup 1.0000x reference)
//
#include <hip/hip_runtime.h>
#include <math.h>
#include <float.h>

#define BATCH 8
#define HIGH  256
#define LOWR  64
#define NN    4096          // LOWR*LOWR
#define HIDC  16
#define C1    64

// workspace layout (floats)
#define OFF_XL   0
#define OFF_H1   (OFF_XL  + BATCH*NN)            // 32768
#define OFF_H    (OFF_H1  + BATCH*C1*NN)         // node-major [B*N][16]
#define OFF_SQ   (OFF_H   + BATCH*NN*HIDC)
#define OFF_XP   (OFF_SQ  + BATCH*NN)
#define OFF_ASR  (OFF_XP  + BATCH*NN*HIDC)
#define OFF_ADT  (OFF_ASR + BATCH*NN*4)
#define OFF_P    (OFF_ADT + BATCH*NN*4)
#define OFF_OL   (OFF_P   + BATCH*NN*HIDC)

// ---------------- bilinear downsample 256 -> 64 (antialiased triangle) -------
__global__ void k_down(const float* __restrict__ x, float* __restrict__ xl) {
    int t = blockIdx.x * 256 + threadIdx.x;
    if (t >= BATCH * NN) return;
    int b = t >> 12, oy = (t >> 6) & 63, ox = t & 63;
    const float* xb = x + b * HIGH * HIGH;
    float cy = 4.f * oy + 1.5f, cx = 4.f * ox + 1.5f;
    float wy[8], wx[8], sy = 0.f, sx = 0.f;
#pragma unroll
    for (int k = 0; k < 8; k++) {
        int iy = 4 * oy - 2 + k;
        float w = 1.f - fabsf((float)iy - cy) * 0.25f;
        if (iy < 0 || iy >= HIGH) w = 0.f;
        wy[k] = w; sy += w;
        int ix = 4 * ox - 2 + k;
        float v = 1.f - fabsf((float)ix - cx) * 0.25f;
        if (ix < 0 || ix >= HIGH) v = 0.f;
        wx[k] = v; sx += v;
    }
    float acc = 0.f;
#pragma unroll
    for (int ky = 0; ky < 8; ky++) {
        if (wy[ky] == 0.f) continue;
        int iy = 4 * oy - 2 + ky;
        float rowacc = 0.f;
#pragma unroll
        for (int kx = 0; kx < 8; kx++) {
            if (wx[kx] == 0.f) continue;
            int ix = 4 * ox - 2 + kx;
            rowacc += wx[kx] * xb[iy * HIGH + ix];
        }
        acc += wy[ky] * rowacc;
    }
    xl[t] = acc / (sy * sx);
}

// ---------------- conv3x3 1->64 + BN + relu ---------------------------------
__global__ void k_conv1(const float* __restrict__ xl, const float* __restrict__ W1,
                        const float* __restrict__ b1, const float* __restrict__ g1,
                        const float* __restrict__ be1, const float* __restrict__ m1,
                        const float* __restrict__ v1, float* __restrict__ h1) {
    int t = blockIdx.x * 256 + threadIdx.x;
    if (t >= BATCH * C1 * NN) return;
    int b = t >> 18, co = (t >> 12) & 63, y = (t >> 6) & 63, x = t & 63;
    const float* src = xl + b * NN;
    const float* w = W1 + co * 9;
    float acc = 0.f;
#pragma unroll
    for (int dy = -1; dy <= 1; dy++) {
        int yy = y + dy; if (yy < 0 || yy >= 64) continue;
#pragma unroll
        for (int dx = -1; dx <= 1; dx++) {
            int xx = x + dx; if (xx < 0 || xx >= 64) continue;
            acc += w[(dy + 1) * 3 + (dx + 1)] * src[yy * 64 + xx];
        }
    }
    acc += b1[co];
    float sc = g1[co] / sqrtf(v1[co] + 1e-5f);
    acc = (acc - m1[co]) * sc + be1[co];
    h1[t] = fmaxf(acc, 0.f);
}

// ------- conv3x3 64->16 + BN + relu, fused: h (node-major), sq, xp, asr, adt -
__launch_bounds__(256)
__global__ void k_conv2(const float* __restrict__ h1, const float* __restrict__ W2,
                        const float* __restrict__ b2, const float* __restrict__ g2,
                        const float* __restrict__ be2, const float* __restrict__ m2,
                        const float* __restrict__ v2, const float* __restrict__ Wg,
                        const float* __restrict__ a_src, const float* __restrict__ a_dst,
                        float* __restrict__ h, float* __restrict__ sq,
                        float* __restrict__ xp, float* __restrict__ asr,
                        float* __restrict__ adt) {
    __shared__ float sW2[16 * 64 * 9];
    __shared__ float sWg[256];
    __shared__ float sA[32];
    int tid = threadIdx.x;
    for (int k = tid; k < 9216; k += 256) sW2[k] = W2[k];
    sWg[tid] = Wg[tid & 255];
    if (tid < 16) { sA[tid] = a_src[tid]; sA[16 + tid] = a_dst[tid]; }
    __syncthreads();
    int blk = blockIdx.x;                 // 8 batches * 16 y-tiles
    int b = blk >> 4, ytile = blk & 15;
    int ty = tid >> 6, x = tid & 63, y = ytile * 4 + ty;
    float acc[16];
#pragma unroll
    for (int o = 0; o < 16; o++) acc[o] = 0.f;
    const float* hb = h1 + (long)b * C1 * NN;
    for (int ci = 0; ci < 64; ci++) {
        const float* plane = hb + ci * NN;
#pragma unroll
        for (int dy = -1; dy <= 1; dy++) {
            int yy = y + dy; bool oky = (yy >= 0 && yy < 64);
#pragma unroll
            for (int dx = -1; dx <= 1; dx++) {
                int xx = x + dx;
                float v = (oky && xx >= 0 && xx < 64) ? plane[yy * 64 + xx] : 0.f;
                int widx = ci * 9 + (dy + 1) * 3 + (dx + 1);
#pragma unroll
                for (int o = 0; o < 16; o++) acc[o] += v * sW2[o * 576 + widx];
            }
        }
    }
    int n = y * 64 + x;
    long node = (long)b * NN + n;
    float nodev[16], sqv = 0.f;
#pragma unroll
    for (int o = 0; o < 16; o++) {
        float a = acc[o] + b2[o];
        float sc = g2[o] / sqrtf(v2[o] + 1e-5f);
        a = (a - m2[o]) * sc + be2[o];
        a = fmaxf(a, 0.f);
        nodev[o] = a; sqv += a * a;
        h[node * 16 + o] = a;
    }
    sq[node] = sqv;
    float xpv[16];
#pragma unroll
    for (int o = 0; o < 16; o++) {
        float a = 0.f;
#pragma unroll
        for (int c = 0; c < 16; c++) a += sWg[o * 16 + c] * nodev[c];
        xpv[o] = a;
        xp[node * 16 + o] = a;
    }
#pragma unroll
    for (int hh = 0; hh < 4; hh++) {
        float as = 0.f, ad = 0.f;
#pragma unroll
        for (int f = 0; f < 4; f++) {
            as += xpv[hh * 4 + f] * sA[hh * 4 + f];
            ad += xpv[hh * 4 + f] * sA[16 + hh * 4 + f];
        }
        asr[node * 4 + hh] = as;
        adt[node * 4 + hh] = ad;
    }
}

// --------- kNN (K=8, excl self) + GAT(4 heads) + bias + relu -> p -----------
// block = 256 threads = 64 rows x 4 j-segments; grid = 8 batches * 64 row-blocks
__launch_bounds__(256)
__global__ void k_gat(const float* __restrict__ h, const float* __restrict__ sq,
                      const float* __restrict__ xp, const float* __restrict__ asr,
                      const float* __restrict__ adt, const float* __restrict__ bg,
                      float* __restrict__ p) {
    __shared__ float tileN[256 * 16];
    __shared__ float tileSq[256];
    __shared__ float md[256 * 8];
    __shared__ int   mi[256 * 8];
    int tid = threadIdx.x;
    int blk = blockIdx.x;
    int b = blk >> 6;
    int rowbase = (blk & 63) * 64;
    int r = tid & 63, seg = tid >> 6;
    int i = rowbase + r;
    long bN = (long)b * NN;
    const float4* nip = (const float4*)&h[(bN + i) * 16];
    float4 ni0 = nip[0], ni1 = nip[1], ni2 = nip[2], ni3 = nip[3];
    float sqi = sq[bN + i];
    float dist[8]; int idx[8];
#pragma unroll
    for (int k = 0; k < 8; k++) { dist[k] = FLT_MAX; idx[k] = 0x7FFFFFFF; }

    for (int tile = 0; tile < 16; tile++) {
        int jbase = tile * 256;
        __syncthreads();
        {   // cooperative stage: thread tid loads node jbase+tid
            const float4* src = (const float4*)&h[(bN + jbase + tid) * 16];
            float4* dst = (float4*)&tileN[tid * 16];
            dst[0] = src[0]; dst[1] = src[1]; dst[2] = src[2]; dst[3] = src[3];
            tileSq[tid] = sq[bN + jbase + tid];
        }
        __syncthreads();
        for (int jj = seg; jj < 256; jj += 4) {   // whole wave shares seg -> LDS broadcast
            const float4* tn = (const float4*)&tileN[jj * 16];
            float4 a0 = tn[0], a1 = tn[1], a2 = tn[2], a3 = tn[3];
            float dot = ni0.x * a0.x + ni0.y * a0.y + ni0.z * a0.z + ni0.w * a0.w
                      + ni1.x * a1.x + ni1.y * a1.y + ni1.z * a1.z + ni1.w * a1.w
                      + ni2.x * a2.x + ni2.y * a2.y + ni2.z * a2.z + ni2.w * a2.w
                      + ni3.x * a3.x + ni3.y * a3.y + ni3.z * a3.z + ni3.w * a3.w;
            int j = jbase + jj;
            float d = sqi + tileSq[jj] - 2.f * dot;
            if (j == i) d = FLT_MAX;                 // self excluded (diag +1e9)
            if (d < dist[7]) {                       // strict < : lowest-index tie-break
                dist[7] = d; idx[7] = j;
#pragma unroll
                for (int k = 7; k > 0; k--) {
                    if (dist[k] < dist[k - 1]) {
                        float td = dist[k]; dist[k] = dist[k - 1]; dist[k - 1] = td;
                        int tj = idx[k]; idx[k] = idx[k - 1]; idx[k - 1] = tj;
                    }
                }
            }
        }
    }
    __syncthreads();
#pragma unroll
    for (int k = 0; k < 8; k++) { md[tid * 8 + k] = dist[k]; mi[tid * 8 + k] = idx[k]; }
    __syncthreads();

    if (tid < 64) {
        // merge 4 segment lists, lexicographic (d, idx) to match jax top_k ties
        float fD[8]; int fI[8];
#pragma unroll
        for (int k = 0; k < 8; k++) { fD[k] = FLT_MAX; fI[k] = 0x7FFFFFFF; }
        for (int s = 0; s < 4; s++) {
            int src = (r + s * 64) * 8;
#pragma unroll
            for (int k = 0; k < 8; k++) {
                float d = md[src + k]; int j = mi[src + k];
                bool lt = (d < fD[7]) || (d == fD[7] && j < fI[7]);
                if (lt) {
                    fD[7] = d; fI[7] = j;
#pragma unroll
                    for (int q = 7; q > 0; q--) {
                        bool sw = (fD[q] < fD[q - 1]) || (fD[q] == fD[q - 1] && fI[q] < fI[q - 1]);
                        if (sw) {
                            float td = fD[q]; fD[q] = fD[q - 1]; fD[q - 1] = td;
                            int tj = fI[q]; fI[q] = fI[q - 1]; fI[q - 1] = tj;
                        }
                    }
                }
            }
        }
        int nbrs[9];
#pragma unroll
        for (int e = 0; e < 8; e++) nbrs[e] = fI[e];
        nbrs[8] = i;                                   // self-loop
        float adtv[4];
#pragma unroll
        for (int hh = 0; hh < 4; hh++) adtv[hh] = adt[(bN + i) * 4 + hh];
        float mx[4] = { -FLT_MAX, -FLT_MAX, -FLT_MAX, -FLT_MAX };
#pragma unroll
        for (int e = 0; e < 9; e++) {
            long nb = bN + nbrs[e];
#pragma unroll
            for (int hh = 0; hh < 4; hh++) {
                float l = asr[nb * 4 + hh] + adtv[hh];
                l = (l > 0.f) ? l : 0.2f * l;          // leaky_relu 0.2
                mx[hh] = fmaxf(mx[hh], l);
            }
        }
        float sum[4] = { 0, 0, 0, 0 };
        float acc[16];
#pragma unroll
        for (int c = 0; c < 16; c++) acc[c] = 0.f;
#pragma unroll
        for (int e = 0; e < 9; e++) {
            long nb = bN + nbrs[e];
            float wv[4];
#pragma unroll
            for (int hh = 0; hh < 4; hh++) {
                float l = asr[nb * 4 + hh] + adtv[hh];
                l = (l > 0.f) ? l : 0.2f * l;
                float w = expf(l - mx[hh]);
                sum[hh] += w; wv[hh] = w;
            }
#pragma unroll
            for (int hh = 0; hh < 4; hh++)
#pragma unroll
                for (int f = 0; f < 4; f++)
                    acc[hh * 4 + f] += wv[hh] * xp[nb * 16 + hh * 4 + f];
        }
#pragma unroll
        for (int hh = 0; hh < 4; hh++) {
            float inv = 1.f / sum[hh];
#pragma unroll
            for (int f = 0; f < 4; f++) {
                float o = acc[hh * 4 + f] * inv + bg[hh * 4 + f];
                p[(bN + i) * 16 + hh * 4 + f] = fmaxf(o, 0.f);
            }
        }
    }
}

// ------- 1x1 MLP 16->128->16, fire mask, h += mask*u, 1x1->1 + sigmoid ------
__launch_bounds__(256)
__global__ void k_update(const float* __restrict__ p, const float* __restrict__ h,
                         const float* __restrict__ fire, const float* __restrict__ Wu1,
                         const float* __restrict__ bu1, const float* __restrict__ Wu2,
                         const float* __restrict__ bu2, const float* __restrict__ Wo,
                         const float* __restrict__ bo, float* __restrict__ out_low) {
    __shared__ float sU1[128 * 16];
    __shared__ float sU2[16 * 128];
    __shared__ float sb1[128];
    int tid = threadIdx.x;
    for (int k = tid; k < 2048; k += 256) { sU1[k] = Wu1[k]; sU2[k] = Wu2[k]; }
    if (tid < 128) sb1[tid] = bu1[tid];
    __syncthreads();
    long n = (long)blockIdx.x * 256 + tid;           // 0..32767
    const float4* pp = (const float4*)&p[n * 16];
    float4 p0 = pp[0], p1 = pp[1], p2 = pp[2], p3 = pp[3];
    float pv[16] = { p0.x,p0.y,p0.z,p0.w, p1.x,p1.y,p1.z,p1.w,
                     p2.x,p2.y,p2.z,p2.w, p3.x,p3.y,p3.z,p3.w };
    float u[16];
#pragma unroll
    for (int c = 0; c < 16; c++) u[c] = bu2[c];
    for (int hd = 0; hd < 128; hd++) {
        float a = sb1[hd];
#pragma unroll
        for (int c = 0; c < 16; c++) a += sU1[hd * 16 + c] * pv[c];
        a = fmaxf(a, 0.f);
#pragma unroll
        for (int c = 0; c < 16; c++) u[c] += sU2[c * 128 + hd] * a;
    }
    float mask = (fire[n] < 0.5f) ? 1.f : 0.f;
    float o = bo[0];
#pragma unroll
    for (int c = 0; c < 16; c++) {
        float hn = h[n * 16 + c] + mask * u[c];
        o += Wo[c] * hn;
    }
    out_low[n] = 1.f / (1.f + expf(-o));
}

// ---------------- bilinear upsample 64 -> 256 (half-pixel, clamp) -----------
__global__ void k_up(const float* __restrict__ ol, float* __restrict__ out) {
    int t = blockIdx.x * 256 + threadIdx.x;
    if (t >= BATCH * HIGH * HIGH) return;
    int b = t >> 16, oy = (t >> 8) & 255, ox = t & 255;
    float cy = (oy + 0.5f) * 0.25f - 0.5f;
    float cx = (ox + 0.5f) * 0.25f - 0.5f;
    int iy0 = (int)floorf(cy); float fy = cy - (float)iy0;
    int ix0 = (int)floorf(cx); float fx = cx - (float)ix0;
    int y0 = min(max(iy0, 0), 63), y1 = min(max(iy0 + 1, 0), 63);
    int x0 = min(max(ix0, 0), 63), x1 = min(max(ix0 + 1, 0), 63);
    const float* s = ol + b * NN;
    float v = (1.f - fy) * ((1.f - fx) * s[y0 * 64 + x0] + fx * s[y0 * 64 + x1])
            + fy * ((1.f - fx) * s[y1 * 64 + x0] + fx * s[y1 * 64 + x1]);
    out[t] = v;
}

extern "C" void kernel_launch(void* const* d_in, const int* in_sizes, int n_in,
                              void* d_out, int out_size, void* d_ws, size_t ws_size,
                              hipStream_t stream) {
    const float* x    = (const float*)d_in[0];
    const float* fire = (const float*)d_in[1];
    const float* W1   = (const float*)d_in[2];
    const float* b1   = (const float*)d_in[3];
    const float* g1   = (const float*)d_in[4];
    const float* be1  = (const float*)d_in[5];
    const float* m1   = (const float*)d_in[6];
    const float* v1   = (const float*)d_in[7];
    const float* W2   = (const float*)d_in[8];
    const float* b2   = (const float*)d_in[9];
    const float* g2   = (const float*)d_in[10];
    const float* be2  = (const float*)d_in[11];
    const float* m2   = (const float*)d_in[12];
    const float* v2   = (const float*)d_in[13];
    const float* Wg   = (const float*)d_in[14];
    const float* a_src= (const float*)d_in[15];
    const float* a_dst= (const float*)d_in[16];
    const float* bg   = (const float*)d_in[17];
    const float* Wu1  = (const float*)d_in[18];
    const float* bu1  = (const float*)d_in[19];
    const float* Wu2  = (const float*)d_in[20];
    const float* bu2  = (const float*)d_in[21];
    const float* Wo   = (const float*)d_in[22];
    const float* bo   = (const float*)d_in[23];

    float* ws  = (float*)d_ws;
    float* xl  = ws + OFF_XL;
    float* h1  = ws + OFF_H1;
    float* h   = ws + OFF_H;
    float* sq  = ws + OFF_SQ;
    float* xp  = ws + OFF_XP;
    float* asr = ws + OFF_ASR;
    float* adt = ws + OFF_ADT;
    float* p   = ws + OFF_P;
    float* ol  = ws + OFF_OL;

    k_down  <<<(BATCH * NN + 255) / 256, 256, 0, stream>>>(x, xl);
    k_conv1 <<<(BATCH * C1 * NN) / 256, 256, 0, stream>>>(xl, W1, b1, g1, be1, m1, v1, h1);
    k_conv2 <<<BATCH * 16, 256, 0, stream>>>(h1, W2, b2, g2, be2, m2, v2, Wg, a_src, a_dst,
                                             h, sq, xp, asr, adt);
    k_gat   <<<BATCH * 64, 256, 0, stream>>>(h, sq, xp, asr, adt, bg, p);
    k_update<<<BATCH * NN / 256, 256, 0, stream>>>(p, h, fire, Wu1, bu1, Wu2, bu2, Wo, bo, ol);
    k_up    <<<(BATCH * HIGH * HIGH) / 256, 256, 0, stream>>>(ol, (float*)d_out);
}